// Round 1
// baseline (386.248 us; speedup 1.0000x reference)
//
#include <hip/hip_runtime.h>
#include <hip/hip_bf16.h>
#include <stdint.h>

// Problem constants
#define B_  4
#define S_  2048
#define D_  1024
#define H_  16
#define DH_ 64
#define M_  (B_*S_)   // 8192 tokens

typedef __attribute__((ext_vector_type(8))) short          bf16x8;
typedef __attribute__((ext_vector_type(4))) float          f32x4;
typedef __attribute__((ext_vector_type(4))) unsigned short u16x4;
typedef __attribute__((ext_vector_type(8))) unsigned short u16x8;

__device__ __forceinline__ unsigned short f2bf(float x){
  union { float f; uint32_t u; } v; v.f = x;
  uint32_t r = v.u + 0x7fffu + ((v.u >> 16) & 1u);
  return (unsigned short)(r >> 16);
}

// ---------------------------------------------------------------- fp32 -> bf16
__global__ void cvt_bf16(const float* __restrict__ src,
                         unsigned short* __restrict__ dst, int n8){
  int i = blockIdx.x * blockDim.x + threadIdx.x;
  if (i >= n8) return;
  const float4* s = (const float4*)src + (size_t)i*2;
  float4 a = s[0], b = s[1];
  u16x8 o;
  o[0]=f2bf(a.x); o[1]=f2bf(a.y); o[2]=f2bf(a.z); o[3]=f2bf(a.w);
  o[4]=f2bf(b.x); o[5]=f2bf(b.y); o[6]=f2bf(b.z); o[7]=f2bf(b.w);
  *((u16x8*)dst + i) = o;
}

// ---------------------------------------------------------------- QKV GEMM
// out[m,n] = sum_k hs[m,k] * W[n,k] + bias[n]   (both operands k-contiguous)
// 128x128 tile, BK=64, 4 waves each computing 64x64.
// z=0: Q (scaled by 0.125) -> [B,H,S,DH]; z=1: K -> [B,H,S,DH]; z=2: V -> [B,H,DH,S]
__global__ __launch_bounds__(256) void qkv_gemm(
    const unsigned short* __restrict__ hsb,
    const unsigned short* __restrict__ Wqb,
    const unsigned short* __restrict__ Wkb,
    const unsigned short* __restrict__ Wvb,
    const float* __restrict__ bq, const float* __restrict__ bk,
    const float* __restrict__ bv,
    unsigned short* __restrict__ Qb, unsigned short* __restrict__ Kb,
    unsigned short* __restrict__ Vt)
{
  __shared__ char As[128*128];   // 128 rows x 64 bf16 (128B/row), swizzled
  __shared__ char Bs[128*128];

  const int tid  = threadIdx.x;
  const int z    = blockIdx.z;
  const unsigned short* Wsel = (z==0) ? Wqb : (z==1) ? Wkb : Wvb;
  const float*          bias = (z==0) ? bq  : (z==1) ? bk  : bv;
  const int bm = blockIdx.x * 128, bn = blockIdx.y * 128;
  const int lane = tid & 63, wave = tid >> 6;
  const int g = lane >> 4, c = lane & 15;
  const int wr = wave >> 1, wc = wave & 1;

  f32x4 acc[4][4];
  #pragma unroll
  for (int i=0;i<4;++i)
    #pragma unroll
    for (int j=0;j<4;++j) acc[i][j] = (f32x4){0.f,0.f,0.f,0.f};

  for (int kt=0; kt<16; ++kt){
    const int k0 = kt*64;
    #pragma unroll
    for (int p=0;p<4;++p){              // stage 16KB A + 16KB B, reg->swizzled LDS
      int idx  = p*256 + tid;           // 0..1023 -> row 0..127, 8 x 16B chunks
      int row  = idx >> 3;
      int coff = (idx & 7) << 4;
      int laddr = (row*128 + coff) ^ ((row & 7) << 4);
      *(uint4*)&As[laddr] =
        *(const uint4*)((const char*)hsb  + (size_t)((bm+row)*1024 + k0)*2 + coff);
      *(uint4*)&Bs[laddr] =
        *(const uint4*)((const char*)Wsel + (size_t)((bn+row)*1024 + k0)*2 + coff);
    }
    __syncthreads();
    #pragma unroll
    for (int ks=0; ks<2; ++ks){
      bf16x8 af[4], bfr[4];
      #pragma unroll
      for (int mt=0;mt<4;++mt){
        int row = wr*64 + mt*16 + c;
        af[mt] = *(const bf16x8*)&As[(row*128 + ks*64 + g*16) ^ ((row&7)<<4)];
      }
      #pragma unroll
      for (int nt=0;nt<4;++nt){
        int row = wc*64 + nt*16 + c;
        bfr[nt] = *(const bf16x8*)&Bs[(row*128 + ks*64 + g*16) ^ ((row&7)<<4)];
      }
      #pragma unroll
      for (int mt=0;mt<4;++mt)
        #pragma unroll
        for (int nt=0;nt<4;++nt)
          acc[mt][nt] = __builtin_amdgcn_mfma_f32_16x16x32_bf16(
                          af[mt], bfr[nt], acc[mt][nt], 0, 0, 0);
    }
    __syncthreads();
  }

  const float qscale = (z==0) ? 0.125f : 1.0f;   // 1/sqrt(64) folded into Q
  if (z == 2){
    // V -> Vt[b][h][dh][s]  (transposed so PV B-operand is k-contiguous)
    #pragma unroll
    for (int nt=0;nt<4;++nt){
      int n = bn + wc*64 + nt*16 + c;
      float bb = bias[n];
      int h = n >> 6, dh = n & 63;
      #pragma unroll
      for (int mt=0;mt<4;++mt){
        int m0 = bm + wr*64 + mt*16 + g*4;
        int bi = m0 >> 11, s0 = m0 & 2047;     // 4 consecutive s per lane
        u16x4 o;
        #pragma unroll
        for (int r=0;r<4;++r) o[r] = f2bf(acc[mt][nt][r] + bb);
        *(u16x4*)(Vt + ((size_t)((bi*H_ + h)*DH_ + dh))*S_ + s0) = o;
      }
    }
  } else {
    unsigned short* dst = (z==0) ? Qb : Kb;
    #pragma unroll
    for (int nt=0;nt<4;++nt){
      int n = bn + wc*64 + nt*16 + c;
      float bb = bias[n];
      int h = n >> 6, dh = n & 63;
      #pragma unroll
      for (int mt=0;mt<4;++mt)
        #pragma unroll
        for (int r=0;r<4;++r){
          int m = bm + wr*64 + mt*16 + g*4 + r;
          int bi = m >> 11, s = m & 2047;
          dst[((size_t)((bi*H_ + h)*S_ + s))*DH_ + dh] =
            f2bf((acc[mt][nt][r] + bb)*qscale);
        }
    }
  }
}

// ---------------------------------------------------------------- fused attention
// One block per (b, h, 64 q-rows). 4 waves x 16 q-rows. KV tiles of 64,
// online softmax in fp32, P relayout via per-wave swizzled LDS.
__global__ __launch_bounds__(256) void attn_fwd(
    const unsigned short* __restrict__ Qb,
    const unsigned short* __restrict__ Kb,
    const unsigned short* __restrict__ Vt,
    const float* __restrict__ mask,
    float* __restrict__ out)
{
  __shared__ char Ks[64*128];    // 64 keys x 64 d bf16, swizzled
  __shared__ char Vs[64*128];    // 64 d   x 64 keys bf16 (V^T), swizzled
  __shared__ char Ps[4*16*128];  // per-wave 16 q x 64 keys bf16, swizzled

  const int tid  = threadIdx.x;
  const int wave = tid >> 6, lane = tid & 63;
  const int g = lane >> 4, c = lane & 15;
  const int b = blockIdx.z, h = blockIdx.y;
  const int qw = blockIdx.x*64 + wave*16;

  const unsigned short* Qh = Qb + (size_t)(b*H_ + h)*S_*DH_;
  const unsigned short* Kh = Kb + (size_t)(b*H_ + h)*S_*DH_;
  const unsigned short* Vh = Vt + (size_t)(b*H_ + h)*DH_*S_;
  const float* mrow = mask + (size_t)b*S_;

  bf16x8 qf[2];                  // Q rows held in registers for whole kernel
  #pragma unroll
  for (int ks=0;ks<2;++ks)
    qf[ks] = *(const bf16x8*)(Qh + (size_t)(qw + c)*DH_ + ks*32 + g*8);

  f32x4 o[4];
  #pragma unroll
  for (int dt=0;dt<4;++dt) o[dt] = (f32x4){0.f,0.f,0.f,0.f};
  float Mm[4] = {-1e30f,-1e30f,-1e30f,-1e30f};
  float Ll[4] = {0.f,0.f,0.f,0.f};
  char* Pw = Ps + wave*2048;

  for (int j=0;j<32;++j){
    const int kv0 = j*64;
    #pragma unroll
    for (int p=0;p<2;++p){       // stage K-tile + Vt-tile (8KB each)
      int idx  = p*256 + tid;    // 0..511 -> row 0..63, 8 x 16B chunks
      int row  = idx >> 3;
      int coff = (idx & 7) << 4;
      int laddr = (row*128 + coff) ^ ((row & 7) << 4);
      *(uint4*)&Ks[laddr] =
        *(const uint4*)((const char*)Kh + (size_t)((kv0+row)*DH_)*2 + coff);
      *(uint4*)&Vs[laddr] =
        *(const uint4*)((const char*)Vh + (size_t)(row*S_ + kv0)*2 + coff);
    }
    __syncthreads();

    // scores S = Q K^T  (Q pre-scaled by 1/8)
    f32x4 sc[4];
    #pragma unroll
    for (int nt=0;nt<4;++nt) sc[nt] = (f32x4){0.f,0.f,0.f,0.f};
    #pragma unroll
    for (int ks=0;ks<2;++ks)
      #pragma unroll
      for (int nt=0;nt<4;++nt){
        int row = nt*16 + c;     // key row
        bf16x8 kf = *(const bf16x8*)&Ks[(row*128 + ks*64 + g*16) ^ ((row&7)<<4)];
        sc[nt] = __builtin_amdgcn_mfma_f32_16x16x32_bf16(qf[ks], kf, sc[nt], 0,0,0);
      }

    // additive mask (broadcast over q-rows)
    #pragma unroll
    for (int nt=0;nt<4;++nt){
      float mv = mrow[kv0 + nt*16 + c];
      #pragma unroll
      for (int r=0;r<4;++r) sc[nt][r] += mv;
    }

    // online softmax; row r of this lane = q (g*4+r), cols spread over 16 lanes
    #pragma unroll
    for (int r=0;r<4;++r){
      float tm = fmaxf(fmaxf(sc[0][r],sc[1][r]), fmaxf(sc[2][r],sc[3][r]));
      tm = fmaxf(tm, __shfl_xor(tm,1));
      tm = fmaxf(tm, __shfl_xor(tm,2));
      tm = fmaxf(tm, __shfl_xor(tm,4));
      tm = fmaxf(tm, __shfl_xor(tm,8));
      float mn = fmaxf(Mm[r], tm);
      float al = __expf(Mm[r] - mn);
      float rs = 0.f;
      #pragma unroll
      for (int nt=0;nt<4;++nt){
        float p = __expf(sc[nt][r] - mn);
        sc[nt][r] = p;
        rs += p;
      }
      rs += __shfl_xor(rs,1); rs += __shfl_xor(rs,2);
      rs += __shfl_xor(rs,4); rs += __shfl_xor(rs,8);
      Ll[r] = Ll[r]*al + rs;
      Mm[r] = mn;
      #pragma unroll
      for (int dt=0;dt<4;++dt) o[dt][r] *= al;
    }

    // P (D-frag layout) -> per-wave LDS -> A-frag layout for PV
    #pragma unroll
    for (int nt=0;nt<4;++nt)
      #pragma unroll
      for (int r=0;r<4;++r){
        int row = g*4 + r;
        *(unsigned short*)&Pw[(row*128 + (nt*16+c)*2) ^ ((row&7)<<4)] =
          f2bf(sc[nt][r]);
      }
    asm volatile("s_waitcnt lgkmcnt(0)" ::: "memory");  // wave-local ds_write->ds_read

    // O += P V  (A = P from LDS, B = V^T rows from LDS)
    #pragma unroll
    for (int ks=0;ks<2;++ks){
      bf16x8 pa = *(const bf16x8*)&Pw[(c*128 + ks*64 + g*16) ^ ((c&7)<<4)];
      #pragma unroll
      for (int dt=0;dt<4;++dt){
        int row = dt*16 + c;     // d row of V^T
        bf16x8 vf = *(const bf16x8*)&Vs[(row*128 + ks*64 + g*16) ^ ((row&7)<<4)];
        o[dt] = __builtin_amdgcn_mfma_f32_16x16x32_bf16(pa, vf, o[dt], 0,0,0);
      }
    }
    __syncthreads();
  }

  // epilogue: normalize and write [B,S,D] fp32 (coalesced 64B per 16 lanes)
  #pragma unroll
  for (int r=0;r<4;++r){
    float inv = 1.0f / Ll[r];
    int q = qw + g*4 + r;
    float* orow = out + ((size_t)b*S_ + q)*D_ + h*DH_;
    #pragma unroll
    for (int dt=0;dt<4;++dt) orow[dt*16 + c] = o[dt][r]*inv;
  }
}

// ---------------------------------------------------------------- launch
extern "C" void kernel_launch(void* const* d_in, const int* in_sizes, int n_in,
                              void* d_out, int out_size, void* d_ws, size_t ws_size,
                              hipStream_t stream)
{
  (void)in_sizes; (void)n_in; (void)out_size; (void)ws_size;
  const float* hs   = (const float*)d_in[0];
  const float* mask = (const float*)d_in[1];
  const float* Wq   = (const float*)d_in[2];
  const float* bq   = (const float*)d_in[3];
  const float* Wk   = (const float*)d_in[4];
  const float* bk   = (const float*)d_in[5];
  const float* Wv   = (const float*)d_in[6];
  const float* bv   = (const float*)d_in[7];
  float* out = (float*)d_out;

  char* ws = (char*)d_ws;
  unsigned short* hsb = (unsigned short*)(ws);              // 16 MB
  unsigned short* Wqb = (unsigned short*)(ws + 16777216);   //  2 MB
  unsigned short* Wkb = (unsigned short*)(ws + 18874368);   //  2 MB
  unsigned short* Wvb = (unsigned short*)(ws + 20971520);   //  2 MB
  unsigned short* Qb  = (unsigned short*)(ws + 23068672);   // 16 MB [B,H,S,DH]
  unsigned short* Kb  = (unsigned short*)(ws + 39845888);   // 16 MB [B,H,S,DH]
  unsigned short* Vt  = (unsigned short*)(ws + 56623104);   // 16 MB [B,H,DH,S]

  cvt_bf16<<<4096, 256, 0, stream>>>(hs, hsb, 1048576);     // 8.4M elems
  cvt_bf16<<<512,  256, 0, stream>>>(Wq, Wqb, 131072);
  cvt_bf16<<<512,  256, 0, stream>>>(Wk, Wkb, 131072);
  cvt_bf16<<<512,  256, 0, stream>>>(Wv, Wvb, 131072);

  qkv_gemm<<<dim3(64, 8, 3), 256, 0, stream>>>(
      hsb, Wqb, Wkb, Wvb, bq, bk, bv, Qb, Kb, Vt);

  attn_fwd<<<dim3(S_/64, H_, B_), 256, 0, stream>>>(Qb, Kb, Vt, mask, out);
}

// Round 2
// 269.866 us; speedup vs baseline: 1.4313x; 1.4313x over previous
//
#include <hip/hip_runtime.h>
#include <stdint.h>

#define B_  4
#define S_  2048
#define D_  1024
#define H_  16
#define DH_ 64

typedef short bf16x8 __attribute__((ext_vector_type(8)));
typedef float f32x4v __attribute__((ext_vector_type(4)));
typedef float f32x16 __attribute__((ext_vector_type(16)));
typedef unsigned short u16x4 __attribute__((ext_vector_type(4)));
typedef unsigned short u16x8 __attribute__((ext_vector_type(8)));

typedef const __attribute__((address_space(1))) uint32_t GAS;
typedef __attribute__((address_space(3))) uint32_t LAS;

__device__ __forceinline__ void gload16(const void* g, void* l){
  __builtin_amdgcn_global_load_lds((GAS*)g, (LAS*)l, 16, 0, 0);
}

__device__ __forceinline__ unsigned short f2bf(float x){
  union { float f; uint32_t u; } v; v.f = x;
  uint32_t r = v.u + 0x7fffu + ((v.u >> 16) & 1u);
  return (unsigned short)(r >> 16);
}

__device__ __forceinline__ uint32_t cvtpk(float lo, float hi_){
  uint32_t r;
  asm("v_cvt_pk_bf16_f32 %0, %1, %2" : "=v"(r) : "v"(lo), "v"(hi_));
  return r;
}

__device__ __forceinline__ void plswap(uint32_t& a, uint32_t& b){
  asm volatile("v_permlane32_swap_b32 %0, %1" : "+v"(a), "+v"(b));
}

// ---------------------------------------------------------------- fp32 -> bf16 (hs + 3 weights, z-indexed)
__global__ void cvt_all(const float* __restrict__ hs, const float* __restrict__ Wq,
                        const float* __restrict__ Wk, const float* __restrict__ Wv,
                        unsigned short* __restrict__ hsb, unsigned short* __restrict__ Wqb,
                        unsigned short* __restrict__ Wkb, unsigned short* __restrict__ Wvb){
  const int z = blockIdx.y;
  const float* src = (z==0)?hs:(z==1)?Wq:(z==2)?Wk:Wv;
  unsigned short* dst = (z==0)?hsb:(z==1)?Wqb:(z==2)?Wkb:Wvb;
  const int n8 = (z==0) ? 1048576 : 131072;
  int i = blockIdx.x * blockDim.x + threadIdx.x;
  if (i >= n8) return;
  const float4* s = (const float4*)src + (size_t)i*2;
  float4 a = s[0], b = s[1];
  u16x8 o;
  o[0]=f2bf(a.x); o[1]=f2bf(a.y); o[2]=f2bf(a.z); o[3]=f2bf(a.w);
  o[4]=f2bf(b.x); o[5]=f2bf(b.y); o[6]=f2bf(b.z); o[7]=f2bf(b.w);
  *((u16x8*)dst + i) = o;
}

// ---------------------------------------------------------------- mask -> SC-layout table
// mskT[b][j][hi][v] with v = t*16 + r : mask[b][ j*64 + (r&3)+8*(r>>2)+4*hi+32*t ]
__global__ void mask_sc(const float* __restrict__ mask, float* __restrict__ mskT){
  int idx = blockIdx.x * blockDim.x + threadIdx.x;
  if (idx >= B_*32*2*32) return;
  int b = idx >> 11, rem = idx & 2047;
  int j = rem >> 6, hi = (rem >> 5) & 1, v = rem & 31;
  int r = v & 15, t = v >> 4;
  int key = (r & 3) + ((r >> 2) << 3) + (hi << 2) + (t << 5);
  mskT[idx] = mask[b * S_ + j * 64 + key];
}

// ---------------------------------------------------------------- QKV GEMM (m97-style gload_lds staging)
// out[m,n] = sum_k hs[m,k]*W[n,k] + bias[n].  128x128 tile, BK=64, 4 waves x 64x64.
__global__ __launch_bounds__(256) void qkv_gemm(
    const unsigned short* __restrict__ hsb,
    const unsigned short* __restrict__ Wqb,
    const unsigned short* __restrict__ Wkb,
    const unsigned short* __restrict__ Wvb,
    const float* __restrict__ bq, const float* __restrict__ bk,
    const float* __restrict__ bv,
    unsigned short* __restrict__ Qb, unsigned short* __restrict__ Kb,
    unsigned short* __restrict__ Vt)
{
  __shared__ char As[128*128];   // [128 rows][64 bf16 = 128B], linear
  __shared__ char Bs[128*128];

  const int tid  = threadIdx.x;
  const int z    = blockIdx.z;
  const unsigned short* Wsel = (z==0) ? Wqb : (z==1) ? Wkb : Wvb;
  const float*          bias = (z==0) ? bq  : (z==1) ? bk  : bv;
  const int bm = blockIdx.x * 128, bn = blockIdx.y * 128;
  const int lane = tid & 63, wave = tid >> 6;
  const int g = lane >> 4, c = lane & 15;
  const int wr = wave >> 1, wc = wave & 1;

  f32x4v acc[4][4];
  #pragma unroll
  for (int i=0;i<4;++i)
    #pragma unroll
    for (int j=0;j<4;++j) acc[i][j] = (f32x4v){0.f,0.f,0.f,0.f};

  const int srow = lane >> 3;          // 0..7 within 1KB chunk
  const int scol = (lane & 7) << 4;    // byte col within 128B row

  for (int kt=0; kt<16; ++kt){
    const int k0b = kt*128;            // byte offset of K-chunk within a 2048B row
    #pragma unroll
    for (int cc=0; cc<4; ++cc){
      const int rb = wave*32 + cc*8;   // 8 rows per call
      gload16((const char*)hsb  + (size_t)(bm+rb+srow)*2048 + k0b + scol, &As[rb*128]);
      gload16((const char*)Wsel + (size_t)(bn+rb+srow)*2048 + k0b + scol, &Bs[rb*128]);
    }
    __syncthreads();
    #pragma unroll
    for (int ks=0; ks<2; ++ks){
      bf16x8 af[4], bfr[4];
      #pragma unroll
      for (int mt=0;mt<4;++mt){
        int row = wr*64 + mt*16 + c;
        af[mt] = *(const bf16x8*)&As[row*128 + ks*64 + g*16];
      }
      #pragma unroll
      for (int nt=0;nt<4;++nt){
        int row = wc*64 + nt*16 + c;
        bfr[nt] = *(const bf16x8*)&Bs[row*128 + ks*64 + g*16];
      }
      #pragma unroll
      for (int mt=0;mt<4;++mt)
        #pragma unroll
        for (int nt=0;nt<4;++nt)
          acc[mt][nt] = __builtin_amdgcn_mfma_f32_16x16x32_bf16(
                          af[mt], bfr[nt], acc[mt][nt], 0, 0, 0);
    }
    __syncthreads();
  }

  const float qscale = (z==0) ? 0.125f : 1.0f;   // 1/sqrt(64) folded into Q
  if (z == 2){
    #pragma unroll
    for (int nt=0;nt<4;++nt){
      int n = bn + wc*64 + nt*16 + c;
      float bb = bias[n];
      int h = n >> 6, dh = n & 63;
      #pragma unroll
      for (int mt=0;mt<4;++mt){
        int m0 = bm + wr*64 + mt*16 + g*4;
        int bi = m0 >> 11, s0 = m0 & 2047;
        u16x4 o;
        #pragma unroll
        for (int r=0;r<4;++r) o[r] = f2bf(acc[mt][nt][r] + bb);
        *(u16x4*)(Vt + ((size_t)((bi*H_ + h)*DH_ + dh))*S_ + s0) = o;
      }
    }
  } else {
    unsigned short* dst = (z==0) ? Qb : Kb;
    #pragma unroll
    for (int nt=0;nt<4;++nt){
      int n = bn + wc*64 + nt*16 + c;
      float bb = bias[n];
      int h = n >> 6, dh = n & 63;
      #pragma unroll
      for (int mt=0;mt<4;++mt)
        #pragma unroll
        for (int r=0;r<4;++r){
          int m = bm + wr*64 + mt*16 + g*4 + r;
          int bi = m >> 11, s = m & 2047;
          dst[((size_t)((bi*H_ + h)*S_ + s))*DH_ + dh] =
            f2bf((acc[mt][nt][r] + bb)*qscale);
        }
    }
  }
}

// ---------------------------------------------------------------- fused attention, swapped-QK^T 32x32
// 8 waves x 64 q-rows = 512 q/block. KVBLK=64, double-buffered LDS via global_load_lds
// (linear dest + inverse-swizzled source + XOR-swizzled reads).
// Scores: SC = mfma(K, Q) -> D[key][q], q = lane&31 lane-local. No max-subtraction
// (scores bounded; softmax shift-invariant). P assembled in-register via cvt_pk+permlane32_swap.
// PV: O = mfma(V^T, P) -> O[d][q], q lane-local => per-lane 1/l normalize.
__global__ __launch_bounds__(512, 2) void attn_fwd(
    const unsigned short* __restrict__ Qb,
    const unsigned short* __restrict__ Kb,
    const unsigned short* __restrict__ Vt,
    const float* __restrict__ mskT,
    float* __restrict__ out)
{
  __shared__ char Ks[2][8192];   // [64 keys][64 d bf16], linear rows of 128B
  __shared__ char Vs[2][8192];   // [64 d][64 keys bf16] (V^T)

  const int tid  = threadIdx.x;
  const int wave = tid >> 6, lane = tid & 63;
  const int q32 = lane & 31, hi = lane >> 5;

  // XCD swizzle: 64 (b,h) groups x 4 q-blocks; 8 groups per XCD
  const int raw = blockIdx.x;                  // 0..255
  const int grp = (raw & 7) * 8 + ((raw >> 3) >> 2);
  const int sub = (raw >> 3) & 3;
  const int b = grp >> 4, h = grp & 15;
  const int qbase = sub * 512 + wave * 64;

  const unsigned short* Qh = Qb + (size_t)(b*H_ + h)*S_*DH_;
  const unsigned short* Kh = Kb + (size_t)(b*H_ + h)*S_*DH_;
  const unsigned short* Vh = Vt + (size_t)(b*H_ + h)*DH_*S_;

  // Q fragments (held whole kernel): qf[qc][dc], B-operand (col=q, k = hi*8+i over d)
  bf16x8 qf[2][4];
  #pragma unroll
  for (int qc=0;qc<2;++qc)
    #pragma unroll
    for (int dc=0;dc<4;++dc)
      qf[qc][dc] = *(const bf16x8*)(Qh + (size_t)(qbase + qc*32 + q32)*DH_ + dc*16 + hi*8);

  f32x16 O[2][2];                // [qc][df]: O[d][q], d = (r&3)+8*(r>>2)+4*hi+32*df
  #pragma unroll
  for (int qc=0;qc<2;++qc)
    #pragma unroll
    for (int df=0;df<2;++df)
      #pragma unroll
      for (int e=0;e<16;++e) O[qc][df][e] = 0.f;
  float lsum[2] = {0.f, 0.f};

  const int sr  = wave*8 + (lane>>3);          // staged row 0..63
  const int sc16 = ((lane&7) ^ (lane>>3)) << 4; // inverse-swizzled source byte col

  // prologue stage tile 0 -> buf 0
  gload16((const char*)Kh + (size_t)sr*128  + sc16, &Ks[0][wave*1024]);
  gload16((const char*)Vh + (size_t)sr*4096 + sc16, &Vs[0][wave*1024]);
  __syncthreads();

  const float* mrow = mskT + b*2048 + hi*32;

  for (int j=0;j<32;++j){
    const int bb = j & 1;
    if (j < 31){
      const size_t kv0n = (size_t)(j+1)*64;
      gload16((const char*)Kh + (kv0n + sr)*128        + sc16, &Ks[bb^1][wave*1024]);
      gload16((const char*)Vh + (size_t)sr*4096 + kv0n*2 + sc16, &Vs[bb^1][wave*1024]);
    }
    const char* Kt = Ks[bb];
    const char* Vl = Vs[bb];

    // QK^T: SC[qc][t] = D[key][q] over keys t*32..t*32+31
    f32x16 SC[2][2];
    #pragma unroll
    for (int qc=0;qc<2;++qc)
      #pragma unroll
      for (int t=0;t<2;++t)
        #pragma unroll
        for (int e=0;e<16;++e) SC[qc][t][e] = 0.f;

    #pragma unroll
    for (int t=0;t<2;++t){
      #pragma unroll
      for (int dc=0;dc<4;++dc){
        const int row = t*32 + q32;
        bf16x8 kf = *(const bf16x8*)&Kt[(row*128 + dc*32 + hi*16) ^ ((row&7)<<4)];
        SC[0][t] = __builtin_amdgcn_mfma_f32_32x32x16_bf16(kf, qf[0][dc], SC[0][t], 0,0,0);
        SC[1][t] = __builtin_amdgcn_mfma_f32_32x32x16_bf16(kf, qf[1][dc], SC[1][t], 0,0,0);
      }
    }

    // mask + exp (no max-sub) + per-lane partial row sums
    const float* mj = mrow + j*64;
    #pragma unroll
    for (int t=0;t<2;++t){
      f32x4v m0 = *(const f32x4v*)(mj + t*16 + 0);
      f32x4v m1 = *(const f32x4v*)(mj + t*16 + 4);
      f32x4v m2 = *(const f32x4v*)(mj + t*16 + 8);
      f32x4v m3 = *(const f32x4v*)(mj + t*16 + 12);
      #pragma unroll
      for (int r=0;r<16;++r){
        const float mval = (r<4) ? m0[r&3] : (r<8) ? m1[r&3] : (r<12) ? m2[r&3] : m3[r&3];
        float p0 = __expf(SC[0][t][r] + mval);
        float p1 = __expf(SC[1][t][r] + mval);
        SC[0][t][r] = p0; SC[1][t][r] = p1;
        lsum[0] += p0; lsum[1] += p1;
      }
    }

    // PV per 16-key chunk: build P A-frags in-register, O += mfma(V^T, P)
    #pragma unroll
    for (int kc=0;kc<4;++kc){
      const int t = kc>>1, rb = (kc&1)*8;
      uint32_t w[2][4];
      #pragma unroll
      for (int qc=0;qc<2;++qc){
        uint32_t a  = cvtpk(SC[qc][t][rb+0], SC[qc][t][rb+1]);
        uint32_t b2 = cvtpk(SC[qc][t][rb+4], SC[qc][t][rb+5]);
        uint32_t c2 = cvtpk(SC[qc][t][rb+2], SC[qc][t][rb+3]);
        uint32_t d2 = cvtpk(SC[qc][t][rb+6], SC[qc][t][rb+7]);
        plswap(a, b2);           // -> w0 = {a_lo,b_lo}, w2 = {a_hi,b_hi}
        plswap(c2, d2);          // -> w1, w3
        w[qc][0]=a; w[qc][1]=c2; w[qc][2]=b2; w[qc][3]=d2;
      }
      union PAU { uint32_t u[4]; bf16x8 v; };
      PAU pa0, pa1;
      pa0.u[0]=w[0][0]; pa0.u[1]=w[0][1]; pa0.u[2]=w[0][2]; pa0.u[3]=w[0][3];
      pa1.u[0]=w[1][0]; pa1.u[1]=w[1][1]; pa1.u[2]=w[1][2]; pa1.u[3]=w[1][3];
      #pragma unroll
      for (int df=0;df<2;++df){
        const int row = df*32 + q32;
        bf16x8 vf = *(const bf16x8*)&Vl[(row*128 + kc*32 + hi*16) ^ ((row&7)<<4)];
        O[0][df] = __builtin_amdgcn_mfma_f32_32x32x16_bf16(vf, pa0.v, O[0][df], 0,0,0);
        O[1][df] = __builtin_amdgcn_mfma_f32_32x32x16_bf16(vf, pa1.v, O[1][df], 0,0,0);
      }
    }
    __syncthreads();
  }

  // epilogue: merge half-wave partial sums, normalize, store
  #pragma unroll
  for (int qc=0;qc<2;++qc){
    uint32_t x = __float_as_uint(lsum[qc]), y = x;
    plswap(x, y);
    const float inv = 1.0f / (__uint_as_float(x) + __uint_as_float(y));
    const int q = qbase + qc*32 + q32;
    float* orow = out + ((size_t)b*S_ + q)*D_ + h*DH_;
    #pragma unroll
    for (int df=0;df<2;++df)
      #pragma unroll
      for (int rg=0;rg<4;++rg){
        float4 v4;
        v4.x = O[qc][df][rg*4+0]*inv;
        v4.y = O[qc][df][rg*4+1]*inv;
        v4.z = O[qc][df][rg*4+2]*inv;
        v4.w = O[qc][df][rg*4+3]*inv;
        *(float4*)&orow[df*32 + rg*8 + hi*4] = v4;
      }
  }
}

// ---------------------------------------------------------------- launch
extern "C" void kernel_launch(void* const* d_in, const int* in_sizes, int n_in,
                              void* d_out, int out_size, void* d_ws, size_t ws_size,
                              hipStream_t stream)
{
  (void)in_sizes; (void)n_in; (void)out_size; (void)ws_size;
  const float* hs   = (const float*)d_in[0];
  const float* mask = (const float*)d_in[1];
  const float* Wq   = (const float*)d_in[2];
  const float* bq   = (const float*)d_in[3];
  const float* Wk   = (const float*)d_in[4];
  const float* bk   = (const float*)d_in[5];
  const float* Wv   = (const float*)d_in[6];
  const float* bv   = (const float*)d_in[7];
  float* out = (float*)d_out;

  char* ws = (char*)d_ws;
  unsigned short* hsb = (unsigned short*)(ws);              // 16 MB
  unsigned short* Wqb = (unsigned short*)(ws + 16777216);   //  2 MB
  unsigned short* Wkb = (unsigned short*)(ws + 18874368);   //  2 MB
  unsigned short* Wvb = (unsigned short*)(ws + 20971520);   //  2 MB
  unsigned short* Qb  = (unsigned short*)(ws + 23068672);   // 16 MB [B,H,S,DH]
  unsigned short* Kb  = (unsigned short*)(ws + 39845888);   // 16 MB [B,H,S,DH]
  unsigned short* Vt  = (unsigned short*)(ws + 56623104);   // 16 MB [B,H,DH,S]
  float*          mskT= (float*)(ws + 73400320);            // 32 KB SC-layout mask

  cvt_all<<<dim3(4096, 4), 256, 0, stream>>>(hs, Wq, Wk, Wv, hsb, Wqb, Wkb, Wvb);
  mask_sc<<<32, 256, 0, stream>>>(mask, mskT);

  qkv_gemm<<<dim3(64, 8, 3), 256, 0, stream>>>(
      hsb, Wqb, Wkb, Wvb, bq, bk, bv, Qb, Kb, Vt);

  attn_fwd<<<256, 512, 0, stream>>>(Qb, Kb, Vt, mskT, out);
}

// Round 4
// 269.594 us; speedup vs baseline: 1.4327x; 1.0010x over previous
//
#include <hip/hip_runtime.h>
#include <stdint.h>

#define B_  4
#define S_  2048
#define D_  1024
#define H_  16
#define DH_ 64

#define LOG2E 1.44269504088896340736f

typedef short bf16x8 __attribute__((ext_vector_type(8)));
typedef float f32x4v __attribute__((ext_vector_type(4)));
typedef float f32x16 __attribute__((ext_vector_type(16)));
typedef unsigned short u16x4 __attribute__((ext_vector_type(4)));
typedef unsigned short u16x8 __attribute__((ext_vector_type(8)));

typedef const __attribute__((address_space(1))) uint32_t GAS;
typedef __attribute__((address_space(3))) uint32_t LAS;

__device__ __forceinline__ void gload16(const void* g, void* l){
  __builtin_amdgcn_global_load_lds((GAS*)g, (LAS*)l, 16, 0, 0);
}

__device__ __forceinline__ unsigned short f2bf(float x){
  union { float f; uint32_t u; } v; v.f = x;
  uint32_t r = v.u + 0x7fffu + ((v.u >> 16) & 1u);
  return (unsigned short)(r >> 16);
}

__device__ __forceinline__ uint32_t cvtpk(float lo, float hi_){
  uint32_t r;
  asm("v_cvt_pk_bf16_f32 %0, %1, %2" : "=v"(r) : "v"(lo), "v"(hi_));
  return r;
}

__device__ __forceinline__ void plswap(uint32_t& a, uint32_t& b){
  asm volatile("v_permlane32_swap_b32 %0, %1" : "+v"(a), "+v"(b));
}

// ---------------------------------------------------------------- fp32 -> bf16 (hs + 3 weights)
__global__ void cvt_all(const float* __restrict__ hs, const float* __restrict__ Wq,
                        const float* __restrict__ Wk, const float* __restrict__ Wv,
                        unsigned short* __restrict__ hsb, unsigned short* __restrict__ Wqb,
                        unsigned short* __restrict__ Wkb, unsigned short* __restrict__ Wvb){
  const int z = blockIdx.y;
  const float* src = (z==0)?hs:(z==1)?Wq:(z==2)?Wk:Wv;
  unsigned short* dst = (z==0)?hsb:(z==1)?Wqb:(z==2)?Wkb:Wvb;
  const int n8 = (z==0) ? 1048576 : 131072;
  int i = blockIdx.x * blockDim.x + threadIdx.x;
  if (i >= n8) return;
  const float4* s = (const float4*)src + (size_t)i*2;
  float4 a = s[0], b = s[1];
  u16x8 o;
  o[0]=f2bf(a.x); o[1]=f2bf(a.y); o[2]=f2bf(a.z); o[3]=f2bf(a.w);
  o[4]=f2bf(b.x); o[5]=f2bf(b.y); o[6]=f2bf(b.z); o[7]=f2bf(b.w);
  *((u16x8*)dst + i) = o;
}

// ---------------------------------------------------------------- mask -> SC-layout table (pre-scaled by log2e)
// mskT[b][j][hi][v] with v = t*16 + r : mask[b][ j*64 + (r&3)+8*(r>>2)+4*hi+32*t ] * LOG2E
__global__ void mask_sc(const float* __restrict__ mask, float* __restrict__ mskT){
  int idx = blockIdx.x * blockDim.x + threadIdx.x;
  if (idx >= B_*32*2*32) return;
  int b = idx >> 11, rem = idx & 2047;
  int j = rem >> 6, hi = (rem >> 5) & 1, v = rem & 31;
  int r = v & 15, t = v >> 4;
  int key = (r & 3) + ((r >> 2) << 3) + (hi << 2) + (t << 5);
  mskT[idx] = mask[b * S_ + j * 64 + key] * LOG2E;
}

// ---------------------------------------------------------------- QKV GEMM
// out[m,n] = sum_k hs[m,k]*W[n,k] + bias[n].  128x128 tile, BK=64, 4 waves x 64x64.
// z<2 (Q,K): acc = mfma(W_frag, hs_frag) -> D row = n(dh), col = m(token):
//            lane holds 4 consecutive dh at one token -> u16x4 stores into [B,H,S,DH].
// z==2 (V):  acc = mfma(hs_frag, W_frag) -> lane holds 4 consecutive tokens at one dh
//            -> u16x4 stores into Vt [B,H,DH,S].
__global__ __launch_bounds__(256) void qkv_gemm(
    const unsigned short* __restrict__ hsb,
    const unsigned short* __restrict__ Wqb,
    const unsigned short* __restrict__ Wkb,
    const unsigned short* __restrict__ Wvb,
    const float* __restrict__ bq, const float* __restrict__ bk,
    const float* __restrict__ bv,
    unsigned short* __restrict__ Qb, unsigned short* __restrict__ Kb,
    unsigned short* __restrict__ Vt)
{
  __shared__ char As[128*128];   // [128 rows][64 bf16 = 128B], linear
  __shared__ char Bs[128*128];

  const int tid  = threadIdx.x;
  const int z    = blockIdx.z;
  const unsigned short* Wsel = (z==0) ? Wqb : (z==1) ? Wkb : Wvb;
  const float*          bias = (z==0) ? bq  : (z==1) ? bk  : bv;
  const int bm = blockIdx.x * 128, bn = blockIdx.y * 128;
  const int lane = tid & 63, wave = tid >> 6;
  const int g = lane >> 4, c = lane & 15;
  const int wr = wave >> 1, wc = wave & 1;

  f32x4v acc[4][4];
  #pragma unroll
  for (int i=0;i<4;++i)
    #pragma unroll
    for (int j=0;j<4;++j) acc[i][j] = (f32x4v){0.f,0.f,0.f,0.f};

  const int srow = lane >> 3;          // 0..7 within 1KB chunk
  const int scol = (lane & 7) << 4;    // byte col within 128B row

  for (int kt=0; kt<16; ++kt){
    const int k0b = kt*128;
    #pragma unroll
    for (int cc=0; cc<4; ++cc){
      const int rb = wave*32 + cc*8;
      gload16((const char*)hsb  + (size_t)(bm+rb+srow)*2048 + k0b + scol, &As[rb*128]);
      gload16((const char*)Wsel + (size_t)(bn+rb+srow)*2048 + k0b + scol, &Bs[rb*128]);
    }
    __syncthreads();
    #pragma unroll
    for (int ks=0; ks<2; ++ks){
      bf16x8 af[4], bfr[4];
      #pragma unroll
      for (int mt=0;mt<4;++mt){
        int row = wr*64 + mt*16 + c;
        af[mt] = *(const bf16x8*)&As[row*128 + ks*64 + g*16];
      }
      #pragma unroll
      for (int nt=0;nt<4;++nt){
        int row = wc*64 + nt*16 + c;
        bfr[nt] = *(const bf16x8*)&Bs[row*128 + ks*64 + g*16];
      }
      if (z == 2){
        #pragma unroll
        for (int mt=0;mt<4;++mt)
          #pragma unroll
          for (int nt=0;nt<4;++nt)
            acc[mt][nt] = __builtin_amdgcn_mfma_f32_16x16x32_bf16(
                            af[mt], bfr[nt], acc[mt][nt], 0, 0, 0);
      } else {
        #pragma unroll
        for (int mt=0;mt<4;++mt)
          #pragma unroll
          for (int nt=0;nt<4;++nt)
            acc[mt][nt] = __builtin_amdgcn_mfma_f32_16x16x32_bf16(
                            bfr[nt], af[mt], acc[mt][nt], 0, 0, 0);
      }
    }
    __syncthreads();
  }

  if (z == 2){
    #pragma unroll
    for (int nt=0;nt<4;++nt){
      int n = bn + wc*64 + nt*16 + c;
      float bb = bias[n];
      int h = n >> 6, dh = n & 63;
      #pragma unroll
      for (int mt=0;mt<4;++mt){
        int m0 = bm + wr*64 + mt*16 + g*4;
        int bi = m0 >> 11, s0 = m0 & 2047;
        u16x4 o;
        #pragma unroll
        for (int r=0;r<4;++r) o[r] = f2bf(acc[mt][nt][r] + bb);
        *(u16x4*)(Vt + ((size_t)((bi*H_ + h)*DH_ + dh))*S_ + s0) = o;
      }
    }
  } else {
    // Q gets 1/sqrt(64) * log2e folded in (exp2-based softmax); K plain.
    const float qscale = (z==0) ? 0.125f*LOG2E : 1.0f;
    unsigned short* dst = (z==0) ? Qb : Kb;
    #pragma unroll
    for (int nt=0;nt<4;++nt){
      int n0 = bn + wc*64 + nt*16 + g*4;          // dh-dim, 4 consecutive per lane
      f32x4v bb4 = *(const f32x4v*)&bias[n0];
      int h = n0 >> 6, dh0 = n0 & 63;
      #pragma unroll
      for (int mt=0;mt<4;++mt){
        int m = bm + wr*64 + mt*16 + c;           // token
        int bi = m >> 11, s = m & 2047;
        u16x4 o;
        #pragma unroll
        for (int r=0;r<4;++r) o[r] = f2bf((acc[mt][nt][r] + bb4[r]) * qscale);
        *(u16x4*)(dst + ((size_t)((bi*H_ + h)*S_ + s))*DH_ + dh0) = o;
      }
    }
  }
}

// ---------------------------------------------------------------- fused attention, swapped-QK^T 32x32
// Frag-major LDS: K tile = 8 chunks of 1KB, chunk (t*4+dc) = A-frag (rows=keys t*32..,
// k = d dc*16..) laid out so lane l reads bytes [l*16, l*16+16) -> conflict-free ds_read_b128,
// and global_load_lds (linear wave dest) stages chunk w with per-lane strided source.
// Mask folded into MFMA C-init; softmax via exp2 (Q pre-scaled by 0.125*log2e).
__global__ __launch_bounds__(512, 2) void attn_fwd(
    const unsigned short* __restrict__ Qb,
    const unsigned short* __restrict__ Kb,
    const unsigned short* __restrict__ Vt,
    const float* __restrict__ mskT,
    float* __restrict__ out)
{
  __shared__ char Ks[2][8192];
  __shared__ char Vs[2][8192];

  const int tid  = threadIdx.x;
  const int wave = tid >> 6, lane = tid & 63;
  const int q32 = lane & 31, hi = lane >> 5;

  // XCD swizzle: all 4 q-blocks of a (b,h) group land on one XCD; 8 groups/XCD.
  const int raw = blockIdx.x;                  // 0..255
  const int grp = (raw & 7) * 8 + (raw >> 5);
  const int sub = (raw >> 3) & 3;
  const int b = grp >> 4, h = grp & 15;
  const int qbase = sub * 512 + wave * 64;

  const unsigned short* Qh = Qb + (size_t)(b*H_ + h)*S_*DH_;
  const unsigned short* Kh = Kb + (size_t)(b*H_ + h)*S_*DH_;
  const unsigned short* Vh = Vt + (size_t)(b*H_ + h)*DH_*S_;

  // Q fragments (held whole kernel): qf[qc][dc] = B-operand (col=q, k = d)
  bf16x8 qf[2][4];
  #pragma unroll
  for (int qc=0;qc<2;++qc)
    #pragma unroll
    for (int dc=0;dc<4;++dc)
      qf[qc][dc] = *(const bf16x8*)(Qh + (size_t)(qbase + qc*32 + q32)*DH_ + dc*16 + hi*8);

  f32x16 O[2][2];
  #pragma unroll
  for (int qc=0;qc<2;++qc)
    #pragma unroll
    for (int df=0;df<2;++df)
      #pragma unroll
      for (int e=0;e<16;++e) O[qc][df][e] = 0.f;
  float lsum[2] = {0.f, 0.f};

  // staging source addresses: wave w stages frag chunk w of both K and V tiles.
  // K chunk w=(t*4+dc): lane l -> key t*32+(l&31), d-bytes dc*32 + (l>>5)*16
  const char* Ksrc = (const char*)Kh + (size_t)((wave>>2)*32 + q32)*128 + (wave&3)*32 + hi*16;
  // V chunk w=(df*4+kc): lane l -> d row df*32+(l&31), key-bytes kc*32 + (l>>5)*16
  const char* Vsrc = (const char*)Vh + (size_t)((wave>>2)*32 + q32)*4096 + (wave&3)*32 + hi*16;

  gload16(Ksrc, &Ks[0][wave*1024]);
  gload16(Vsrc, &Vs[0][wave*1024]);
  __syncthreads();

  const float* mrow = mskT + b*2048 + hi*32;

  for (int j=0;j<32;++j){
    const int bb = j & 1;
    if (j < 31){
      gload16(Ksrc + (size_t)(j+1)*64*128, &Ks[bb^1][wave*1024]);
      gload16(Vsrc + (size_t)(j+1)*64*2,   &Vs[bb^1][wave*1024]);
    }
    const char* Kt = Ks[bb];
    const char* Vl = Vs[bb];

    // SC init = mask (already * log2e); same init for both qc.
    const float* mj = mrow + j*64;
    f32x16 SC[2][2];
    #pragma unroll
    for (int t=0;t<2;++t){
      f32x4v m0 = *(const f32x4v*)(mj + t*16 + 0);
      f32x4v m1 = *(const f32x4v*)(mj + t*16 + 4);
      f32x4v m2 = *(const f32x4v*)(mj + t*16 + 8);
      f32x4v m3 = *(const f32x4v*)(mj + t*16 + 12);
      #pragma unroll
      for (int r=0;r<16;++r){
        const float mval = (r<4) ? m0[r&3] : (r<8) ? m1[r&3] : (r<12) ? m2[r&3] : m3[r&3];
        SC[0][t][r] = mval;
        SC[1][t][r] = mval;
      }
    }

    // QK^T: SC[qc][t] += K_frag x Q_frag  (scores already in log2 domain)
    __builtin_amdgcn_s_setprio(1);
    #pragma unroll
    for (int t=0;t<2;++t){
      #pragma unroll
      for (int dc=0;dc<4;++dc){
        bf16x8 kf = *(const bf16x8*)&Kt[((t*4+dc)<<10) + lane*16];
        SC[0][t] = __builtin_amdgcn_mfma_f32_32x32x16_bf16(kf, qf[0][dc], SC[0][t], 0,0,0);
        SC[1][t] = __builtin_amdgcn_mfma_f32_32x32x16_bf16(kf, qf[1][dc], SC[1][t], 0,0,0);
      }
    }
    __builtin_amdgcn_s_setprio(0);

    // p = exp2(score), accumulate row-sum partials
    #pragma unroll
    for (int t=0;t<2;++t)
      #pragma unroll
      for (int r=0;r<16;++r){
        float p0 = __builtin_amdgcn_exp2f(SC[0][t][r]);
        float p1 = __builtin_amdgcn_exp2f(SC[1][t][r]);
        SC[0][t][r] = p0; SC[1][t][r] = p1;
        lsum[0] += p0; lsum[1] += p1;
      }

    // PV per 16-key chunk: build P B-frags in-register, O += mfma(V^T_frag, P)
    #pragma unroll
    for (int kc=0;kc<4;++kc){
      const int t = kc>>1, rb = (kc&1)*8;
      uint32_t w[2][4];
      #pragma unroll
      for (int qc=0;qc<2;++qc){
        uint32_t a  = cvtpk(SC[qc][t][rb+0], SC[qc][t][rb+1]);
        uint32_t b2 = cvtpk(SC[qc][t][rb+4], SC[qc][t][rb+5]);
        uint32_t c2 = cvtpk(SC[qc][t][rb+2], SC[qc][t][rb+3]);
        uint32_t d2 = cvtpk(SC[qc][t][rb+6], SC[qc][t][rb+7]);
        plswap(a, b2);
        plswap(c2, d2);
        w[qc][0]=a; w[qc][1]=c2; w[qc][2]=b2; w[qc][3]=d2;
      }
      union PAU { uint32_t u[4]; bf16x8 v; };
      PAU pa0, pa1;
      pa0.u[0]=w[0][0]; pa0.u[1]=w[0][1]; pa0.u[2]=w[0][2]; pa0.u[3]=w[0][3];
      pa1.u[0]=w[1][0]; pa1.u[1]=w[1][1]; pa1.u[2]=w[1][2]; pa1.u[3]=w[1][3];
      __builtin_amdgcn_s_setprio(1);
      #pragma unroll
      for (int df=0;df<2;++df){
        bf16x8 vf = *(const bf16x8*)&Vl[((df*4+kc)<<10) + lane*16];
        O[0][df] = __builtin_amdgcn_mfma_f32_32x32x16_bf16(vf, pa0.v, O[0][df], 0,0,0);
        O[1][df] = __builtin_amdgcn_mfma_f32_32x32x16_bf16(vf, pa1.v, O[1][df], 0,0,0);
      }
      __builtin_amdgcn_s_setprio(0);
    }
    __syncthreads();
  }

  // epilogue: merge half-wave partial sums, normalize, store
  #pragma unroll
  for (int qc=0;qc<2;++qc){
    uint32_t x = __float_as_uint(lsum[qc]), y = x;
    plswap(x, y);
    const float inv = 1.0f / (__uint_as_float(x) + __uint_as_float(y));
    const int q = qbase + qc*32 + q32;
    float* orow = out + ((size_t)b*S_ + q)*D_ + h*DH_;
    #pragma unroll
    for (int df=0;df<2;++df)
      #pragma unroll
      for (int rg=0;rg<4;++rg){
        float4 v4;
        v4.x = O[qc][df][rg*4+0]*inv;
        v4.y = O[qc][df][rg*4+1]*inv;
        v4.z = O[qc][df][rg*4+2]*inv;
        v4.w = O[qc][df][rg*4+3]*inv;
        *(float4*)&orow[df*32 + rg*8 + hi*4] = v4;
      }
  }
}

// ---------------------------------------------------------------- launch
extern "C" void kernel_launch(void* const* d_in, const int* in_sizes, int n_in,
                              void* d_out, int out_size, void* d_ws, size_t ws_size,
                              hipStream_t stream)
{
  (void)in_sizes; (void)n_in; (void)out_size; (void)ws_size;
  const float* hs   = (const float*)d_in[0];
  const float* mask = (const float*)d_in[1];
  const float* Wq   = (const float*)d_in[2];
  const float* bq   = (const float*)d_in[3];
  const float* Wk   = (const float*)d_in[4];
  const float* bk   = (const float*)d_in[5];
  const float* Wv   = (const float*)d_in[6];
  const float* bv   = (const float*)d_in[7];
  float* out = (float*)d_out;

  char* ws = (char*)d_ws;
  unsigned short* hsb = (unsigned short*)(ws);              // 16 MB
  unsigned short* Wqb = (unsigned short*)(ws + 16777216);   //  2 MB
  unsigned short* Wkb = (unsigned short*)(ws + 18874368);   //  2 MB
  unsigned short* Wvb = (unsigned short*)(ws + 20971520);   //  2 MB
  unsigned short* Qb  = (unsigned short*)(ws + 23068672);   // 16 MB [B,H,S,DH]
  unsigned short* Kb  = (unsigned short*)(ws + 39845888);   // 16 MB [B,H,S,DH]
  unsigned short* Vt  = (unsigned short*)(ws + 56623104);   // 16 MB [B,H,DH,S]
  float*          mskT= (float*)(ws + 73400320);            // 32 KB SC-layout mask

  cvt_all<<<dim3(4096, 4), 256, 0, stream>>>(hs, Wq, Wk, Wv, hsb, Wqb, Wkb, Wvb);
  mask_sc<<<32, 256, 0, stream>>>(mask, mskT);

  qkv_gemm<<<dim3(64, 8, 3), 256, 0, stream>>>(
      hsb, Wqb, Wkb, Wvb, bq, bk, bv, Qb, Kb, Vt);

  attn_fwd<<<256, 512, 0, stream>>>(Qb, Kb, Vt, mskT, out);
}

// Round 7
// 266.060 us; speedup vs baseline: 1.4517x; 1.0133x over previous
//
#include <hip/hip_runtime.h>
#include <stdint.h>

#define B_  4
#define S_  2048
#define D_  1024
#define H_  16
#define DH_ 64

#define LOG2E 1.44269504088896340736f

typedef short bf16x8 __attribute__((ext_vector_type(8)));
typedef float f32x4v __attribute__((ext_vector_type(4)));
typedef float f32x16 __attribute__((ext_vector_type(16)));
typedef unsigned short u16x4 __attribute__((ext_vector_type(4)));
typedef unsigned short u16x8 __attribute__((ext_vector_type(8)));

typedef const __attribute__((address_space(1))) uint32_t GAS;
typedef __attribute__((address_space(3))) uint32_t LAS;

__device__ __forceinline__ void gload16(const void* g, void* l){
  __builtin_amdgcn_global_load_lds((GAS*)g, (LAS*)l, 16, 0, 0);
}

__device__ __forceinline__ unsigned short f2bf(float x){
  union { float f; uint32_t u; } v; v.f = x;
  uint32_t r = v.u + 0x7fffu + ((v.u >> 16) & 1u);
  return (unsigned short)(r >> 16);
}

__device__ __forceinline__ uint32_t cvtpk(float lo, float hi_){
  uint32_t r;
  asm("v_cvt_pk_bf16_f32 %0, %1, %2" : "=v"(r) : "v"(lo), "v"(hi_));
  return r;
}

__device__ __forceinline__ void plswap(uint32_t& a, uint32_t& b){
  asm volatile("v_permlane32_swap_b32 %0, %1" : "+v"(a), "+v"(b));
}

// ---------------------------------------------------------------- fp32 -> bf16 (hs + 3 weights)
__global__ void cvt_all(const float* __restrict__ hs, const float* __restrict__ Wq,
                        const float* __restrict__ Wk, const float* __restrict__ Wv,
                        unsigned short* __restrict__ hsb, unsigned short* __restrict__ Wqb,
                        unsigned short* __restrict__ Wkb, unsigned short* __restrict__ Wvb){
  const int z = blockIdx.y;
  const float* src = (z==0)?hs:(z==1)?Wq:(z==2)?Wk:Wv;
  unsigned short* dst = (z==0)?hsb:(z==1)?Wqb:(z==2)?Wkb:Wvb;
  const int n8 = (z==0) ? 1048576 : 131072;
  int i = blockIdx.x * blockDim.x + threadIdx.x;
  if (i >= n8) return;
  const float4* s = (const float4*)src + (size_t)i*2;
  float4 a = s[0], b = s[1];
  u16x8 o;
  o[0]=f2bf(a.x); o[1]=f2bf(a.y); o[2]=f2bf(a.z); o[3]=f2bf(a.w);
  o[4]=f2bf(b.x); o[5]=f2bf(b.y); o[6]=f2bf(b.z); o[7]=f2bf(b.w);
  *((u16x8*)dst + i) = o;
}

// ---------------------------------------------------------------- mask -> SC-layout table (pre-scaled by log2e)
__global__ void mask_sc(const float* __restrict__ mask, float* __restrict__ mskT){
  int idx = blockIdx.x * blockDim.x + threadIdx.x;
  if (idx >= B_*32*2*32) return;
  int b = idx >> 11, rem = idx & 2047;
  int j = rem >> 6, hi = (rem >> 5) & 1, v = rem & 31;
  int r = v & 15, t = v >> 4;
  int key = (r & 3) + ((r >> 2) << 3) + (hi << 2) + (t << 5);
  mskT[idx] = mask[b * S_ + j * 64 + key] * LOG2E;
}

// ---------------------------------------------------------------- QKV GEMM, async 2-phase dbuf
// out[m,n] = sum_k hs[m,k]*W[n,k] + bias[n].  128x128 tile, BK=64, 4 waves x 64x64.
// Round-4 staging/compute/epilogue unchanged; loop restructured to the attn-proven
// T3-minimum protocol: STAGE(next buf) issued BEFORE computing current buf, one
// vmcnt(0)+barrier per K-step (was stage -> barrier -> compute -> barrier).
__global__ __launch_bounds__(256) void qkv_gemm(
    const unsigned short* __restrict__ hsb,
    const unsigned short* __restrict__ Wqb,
    const unsigned short* __restrict__ Wkb,
    const unsigned short* __restrict__ Wvb,
    const float* __restrict__ bq, const float* __restrict__ bk,
    const float* __restrict__ bv,
    unsigned short* __restrict__ Qb, unsigned short* __restrict__ Kb,
    unsigned short* __restrict__ Vt)
{
  __shared__ char As[2][16384];  // [buf][128 rows][64 bf16 = 128B], linear
  __shared__ char Bs[2][16384];

  const int tid  = threadIdx.x;
  const int z    = blockIdx.z;
  const unsigned short* Wsel = (z==0) ? Wqb : (z==1) ? Wkb : Wvb;
  const float*          bias = (z==0) ? bq  : (z==1) ? bk  : bv;
  const int bm = blockIdx.x * 128, bn = blockIdx.y * 128;
  const int lane = tid & 63, wave = tid >> 6;
  const int g = lane >> 4, c = lane & 15;
  const int wr = wave >> 1, wc = wave & 1;

  f32x4v acc[4][4];
  #pragma unroll
  for (int i=0;i<4;++i)
    #pragma unroll
    for (int j=0;j<4;++j) acc[i][j] = (f32x4v){0.f,0.f,0.f,0.f};

  const int srow = lane >> 3;          // 0..7 within 1KB chunk
  const int scol = (lane & 7) << 4;    // byte col within 128B row

#define STAGE_G(bi, kt_) do {                                                  \
    const int k0b_ = (kt_)*128;                                                \
    _Pragma("unroll")                                                          \
    for (int cc_=0; cc_<4; ++cc_){                                             \
      const int rb_ = wave*32 + cc_*8;                                         \
      gload16((const char*)hsb  + (size_t)(bm+rb_+srow)*2048 + k0b_ + scol,    \
              &As[bi][rb_*128]);                                               \
      gload16((const char*)Wsel + (size_t)(bn+rb_+srow)*2048 + k0b_ + scol,    \
              &Bs[bi][rb_*128]);                                               \
    }                                                                          \
  } while(0)

  STAGE_G(0, 0);
  __syncthreads();

  for (int kt=0; kt<16; ++kt){
    const int bb = kt & 1;
    if (kt < 15) STAGE_G(bb^1, kt+1);
    #pragma unroll
    for (int ks=0; ks<2; ++ks){
      bf16x8 af[4], bfr[4];
      #pragma unroll
      for (int mt=0;mt<4;++mt){
        int row = wr*64 + mt*16 + c;
        af[mt] = *(const bf16x8*)&As[bb][row*128 + ks*64 + g*16];
      }
      #pragma unroll
      for (int nt=0;nt<4;++nt){
        int row = wc*64 + nt*16 + c;
        bfr[nt] = *(const bf16x8*)&Bs[bb][row*128 + ks*64 + g*16];
      }
      if (z == 2){
        #pragma unroll
        for (int mt=0;mt<4;++mt)
          #pragma unroll
          for (int nt=0;nt<4;++nt)
            acc[mt][nt] = __builtin_amdgcn_mfma_f32_16x16x32_bf16(
                            af[mt], bfr[nt], acc[mt][nt], 0, 0, 0);
      } else {
        #pragma unroll
        for (int mt=0;mt<4;++mt)
          #pragma unroll
          for (int nt=0;nt<4;++nt)
            acc[mt][nt] = __builtin_amdgcn_mfma_f32_16x16x32_bf16(
                            bfr[nt], af[mt], acc[mt][nt], 0, 0, 0);
      }
    }
    __syncthreads();
  }

  if (z == 2){
    #pragma unroll
    for (int nt=0;nt<4;++nt){
      int n = bn + wc*64 + nt*16 + c;
      float bb = bias[n];
      int h = n >> 6, dh = n & 63;
      #pragma unroll
      for (int mt=0;mt<4;++mt){
        int m0 = bm + wr*64 + mt*16 + g*4;
        int bi = m0 >> 11, s0 = m0 & 2047;
        u16x4 o;
        #pragma unroll
        for (int r=0;r<4;++r) o[r] = f2bf(acc[mt][nt][r] + bb);
        *(u16x4*)(Vt + ((size_t)((bi*H_ + h)*DH_ + dh))*S_ + s0) = o;
      }
    }
  } else {
    const float qscale = (z==0) ? 0.125f*LOG2E : 1.0f;
    unsigned short* dst = (z==0) ? Qb : Kb;
    #pragma unroll
    for (int nt=0;nt<4;++nt){
      int n0 = bn + wc*64 + nt*16 + g*4;          // dh-dim, 4 consecutive per lane
      f32x4v bb4 = *(const f32x4v*)&bias[n0];
      int h = n0 >> 6, dh0 = n0 & 63;
      #pragma unroll
      for (int mt=0;mt<4;++mt){
        int m = bm + wr*64 + mt*16 + c;           // token
        int bi = m >> 11, s = m & 2047;
        u16x4 o;
        #pragma unroll
        for (int r=0;r<4;++r) o[r] = f2bf((acc[mt][nt][r] + bb4[r]) * qscale);
        *(u16x4*)(dst + ((size_t)((bi*H_ + h)*S_ + s))*DH_ + dh0) = o;
      }
    }
  }
}

// ---------------------------------------------------------------- fused attention, swapped-QK^T 32x32
// EXACT round-4 version (passed, 104.5us): 8 waves x 64 q = 512 q/block, grid 256.
// Frag-major conflict-free LDS; mask in MFMA C-init; exp2 softmax (Q pre-scaled by
// 0.125*log2e); P built in-register via cvt_pk + permlane32_swap.
__global__ __launch_bounds__(512, 2) void attn_fwd(
    const unsigned short* __restrict__ Qb,
    const unsigned short* __restrict__ Kb,
    const unsigned short* __restrict__ Vt,
    const float* __restrict__ mskT,
    float* __restrict__ out)
{
  __shared__ char Ks[2][8192];
  __shared__ char Vs[2][8192];

  const int tid  = threadIdx.x;
  const int wave = tid >> 6, lane = tid & 63;
  const int q32 = lane & 31, hi = lane >> 5;

  // XCD swizzle: all 4 q-blocks of a (b,h) group land on one XCD; 8 groups/XCD.
  const int raw = blockIdx.x;                  // 0..255
  const int grp = (raw & 7) * 8 + (raw >> 5);
  const int sub = (raw >> 3) & 3;
  const int b = grp >> 4, h = grp & 15;
  const int qbase = sub * 512 + wave * 64;

  const unsigned short* Qh = Qb + (size_t)(b*H_ + h)*S_*DH_;
  const unsigned short* Kh = Kb + (size_t)(b*H_ + h)*S_*DH_;
  const unsigned short* Vh = Vt + (size_t)(b*H_ + h)*DH_*S_;

  // Q fragments (held whole kernel): qf[qc][dc] = B-operand (col=q, k = d)
  bf16x8 qf[2][4];
  #pragma unroll
  for (int qc=0;qc<2;++qc)
    #pragma unroll
    for (int dc=0;dc<4;++dc)
      qf[qc][dc] = *(const bf16x8*)(Qh + (size_t)(qbase + qc*32 + q32)*DH_ + dc*16 + hi*8);

  f32x16 O[2][2];
  #pragma unroll
  for (int qc=0;qc<2;++qc)
    #pragma unroll
    for (int df=0;df<2;++df)
      #pragma unroll
      for (int e=0;e<16;++e) O[qc][df][e] = 0.f;
  float lsum[2] = {0.f, 0.f};

  // staging: wave w stages frag chunk w of both K and V tiles.
  // K chunk w=(t*4+dc): lane l -> key t*32+(l&31), d-bytes dc*32+(l>>5)*16
  // V chunk w=(df*4+kc): lane l -> d-row df*32+(l&31), key-bytes kc*32+(l>>5)*16
  const char* Ksrc = (const char*)Kh + (size_t)((wave>>2)*32 + q32)*128 + (wave&3)*32 + hi*16;
  const char* Vsrc = (const char*)Vh + (size_t)((wave>>2)*32 + q32)*4096 + (wave&3)*32 + hi*16;

  gload16(Ksrc, &Ks[0][wave*1024]);
  gload16(Vsrc, &Vs[0][wave*1024]);
  __syncthreads();

  const float* mrow = mskT + b*2048 + hi*32;

  for (int j=0;j<32;++j){
    const int bb = j & 1;
    if (j < 31){
      gload16(Ksrc + (size_t)(j+1)*64*128, &Ks[bb^1][wave*1024]);
      gload16(Vsrc + (size_t)(j+1)*64*2,   &Vs[bb^1][wave*1024]);
    }
    const char* Kt = Ks[bb];
    const char* Vl = Vs[bb];

    // SC init = mask (already * log2e); same init for both qc.
    const float* mj = mrow + j*64;
    f32x16 SC[2][2];
    #pragma unroll
    for (int t=0;t<2;++t){
      f32x4v m0 = *(const f32x4v*)(mj + t*16 + 0);
      f32x4v m1 = *(const f32x4v*)(mj + t*16 + 4);
      f32x4v m2 = *(const f32x4v*)(mj + t*16 + 8);
      f32x4v m3 = *(const f32x4v*)(mj + t*16 + 12);
      #pragma unroll
      for (int r=0;r<16;++r){
        const float mval = (r<4) ? m0[r&3] : (r<8) ? m1[r&3] : (r<12) ? m2[r&3] : m3[r&3];
        SC[0][t][r] = mval;
        SC[1][t][r] = mval;
      }
    }

    // QK^T: SC[qc][t] += K_frag x Q_frag  (scores already in log2 domain)
    __builtin_amdgcn_s_setprio(1);
    #pragma unroll
    for (int t=0;t<2;++t){
      #pragma unroll
      for (int dc=0;dc<4;++dc){
        bf16x8 kf = *(const bf16x8*)&Kt[((t*4+dc)<<10) + lane*16];
        SC[0][t] = __builtin_amdgcn_mfma_f32_32x32x16_bf16(kf, qf[0][dc], SC[0][t], 0,0,0);
        SC[1][t] = __builtin_amdgcn_mfma_f32_32x32x16_bf16(kf, qf[1][dc], SC[1][t], 0,0,0);
      }
    }
    __builtin_amdgcn_s_setprio(0);

    // p = exp2(score), accumulate row-sum partials
    #pragma unroll
    for (int t=0;t<2;++t)
      #pragma unroll
      for (int r=0;r<16;++r){
        float p0 = __builtin_amdgcn_exp2f(SC[0][t][r]);
        float p1 = __builtin_amdgcn_exp2f(SC[1][t][r]);
        SC[0][t][r] = p0; SC[1][t][r] = p1;
        lsum[0] += p0; lsum[1] += p1;
      }

    // PV per 16-key chunk: build P B-frags in-register, O += mfma(V^T_frag, P)
    #pragma unroll
    for (int kc=0;kc<4;++kc){
      const int t = kc>>1, rb = (kc&1)*8;
      uint32_t w[2][4];
      #pragma unroll
      for (int qc=0;qc<2;++qc){
        uint32_t a  = cvtpk(SC[qc][t][rb+0], SC[qc][t][rb+1]);
        uint32_t b2 = cvtpk(SC[qc][t][rb+4], SC[qc][t][rb+5]);
        uint32_t c2 = cvtpk(SC[qc][t][rb+2], SC[qc][t][rb+3]);
        uint32_t d2 = cvtpk(SC[qc][t][rb+6], SC[qc][t][rb+7]);
        plswap(a, b2);
        plswap(c2, d2);
        w[qc][0]=a; w[qc][1]=c2; w[qc][2]=b2; w[qc][3]=d2;
      }
      union PAU { uint32_t u[4]; bf16x8 v; };
      PAU pa0, pa1;
      pa0.u[0]=w[0][0]; pa0.u[1]=w[0][1]; pa0.u[2]=w[0][2]; pa0.u[3]=w[0][3];
      pa1.u[0]=w[1][0]; pa1.u[1]=w[1][1]; pa1.u[2]=w[1][2]; pa1.u[3]=w[1][3];
      __builtin_amdgcn_s_setprio(1);
      #pragma unroll
      for (int df=0;df<2;++df){
        bf16x8 vf = *(const bf16x8*)&Vl[((df*4+kc)<<10) + lane*16];
        O[0][df] = __builtin_amdgcn_mfma_f32_32x32x16_bf16(vf, pa0.v, O[0][df], 0,0,0);
        O[1][df] = __builtin_amdgcn_mfma_f32_32x32x16_bf16(vf, pa1.v, O[1][df], 0,0,0);
      }
      __builtin_amdgcn_s_setprio(0);
    }
    __syncthreads();
  }

  // epilogue: merge half-wave partial sums, normalize, store
  #pragma unroll
  for (int qc=0;qc<2;++qc){
    uint32_t x = __float_as_uint(lsum[qc]), y = x;
    plswap(x, y);
    const float inv = 1.0f / (__uint_as_float(x) + __uint_as_float(y));
    const int q = qbase + qc*32 + q32;
    float* orow = out + ((size_t)b*S_ + q)*D_ + h*DH_;
    #pragma unroll
    for (int df=0;df<2;++df)
      #pragma unroll
      for (int rg=0;rg<4;++rg){
        float4 v4;
        v4.x = O[qc][df][rg*4+0]*inv;
        v4.y = O[qc][df][rg*4+1]*inv;
        v4.z = O[qc][df][rg*4+2]*inv;
        v4.w = O[qc][df][rg*4+3]*inv;
        *(float4*)&orow[df*32 + rg*8 + hi*4] = v4;
      }
  }
}

// ---------------------------------------------------------------- launch
extern "C" void kernel_launch(void* const* d_in, const int* in_sizes, int n_in,
                              void* d_out, int out_size, void* d_ws, size_t ws_size,
                              hipStream_t stream)
{
  (void)in_sizes; (void)n_in; (void)out_size; (void)ws_size;
  const float* hs   = (const float*)d_in[0];
  const float* mask = (const float*)d_in[1];
  const float* Wq   = (const float*)d_in[2];
  const float* bq   = (const float*)d_in[3];
  const float* Wk   = (const float*)d_in[4];
  const float* bk   = (const float*)d_in[5];
  const float* Wv   = (const float*)d_in[6];
  const float* bv   = (const float*)d_in[7];
  float* out = (float*)d_out;

  char* ws = (char*)d_ws;
  unsigned short* hsb = (unsigned short*)(ws);              // 16 MB
  unsigned short* Wqb = (unsigned short*)(ws + 16777216);   //  2 MB
  unsigned short* Wkb = (unsigned short*)(ws + 18874368);   //  2 MB
  unsigned short* Wvb = (unsigned short*)(ws + 20971520);   //  2 MB
  unsigned short* Qb  = (unsigned short*)(ws + 23068672);   // 16 MB [B,H,S,DH]
  unsigned short* Kb  = (unsigned short*)(ws + 39845888);   // 16 MB [B,H,S,DH]
  unsigned short* Vt  = (unsigned short*)(ws + 56623104);   // 16 MB [B,H,DH,S]
  float*          mskT= (float*)(ws + 73400320);            // 32 KB SC-layout mask

  cvt_all<<<dim3(4096, 4), 256, 0, stream>>>(hs, Wq, Wk, Wv, hsb, Wqb, Wkb, Wvb);
  mask_sc<<<32, 256, 0, stream>>>(mask, mskT);

  qkv_gemm<<<dim3(64, 8, 3), 256, 0, stream>>>(
      hsb, Wqb, Wkb, Wvb, bq, bk, bv, Qb, Kb, Vt);

  attn_fwd<<<256, 512, 0, stream>>>(Qb, Kb, Vt, mskT, out);
}